// Round 17
// baseline (163.911 us; speedup 1.0000x reference)
//
#include <hip/hip_runtime.h>

#define NNODES 40000
#define NEDGES 640000
#define NFEAT  256
#define NHID   128

// ---- window partition geometry ----
#define WSH    5                        // 32 nodes per window
#define WNODES 32
#define NW     1250                     // 40000/32 exactly
#define PARTB  250                      // fill blocks
#define EPT    10
#define EPB    2560                     // edges per fill block
#define CSLOTS 16                       // cell = 1 header u64 + 15 record slots
#define CAPREC 15                       // records per cell; lambda=2.05, P(>15)~6e-10
#define CAPW   1024                     // gather srec cap; E[cnt]=512
#define GEMM_BLOCKS (NNODES / 64)       // 625
#define XPAD   264                      // xs row stride (256 + 8 pad) -> 2-way banks = free

// ---- workspace layout (bytes; ws_size = 256 MiB per R9 poison evidence) ----
#define SUP_OFF  0u                     // support bf16: 10,240,000
#define WT_OFF   10240000u              // Wt bf16: 65,536
#define EBIN_OFF 10305536u              // ebin u64 [NW][PARTB][CSLOTS]: 40,000,000
#define WS_NEEDED (EBIN_OFF + (size_t)NW * PARTB * CSLOTS * 8)   // 50,305,536

typedef float floatx4 __attribute__((ext_vector_type(4)));
typedef __bf16 bf16x8 __attribute__((ext_vector_type(8)));
typedef unsigned short ushort8 __attribute__((ext_vector_type(8)));
union BfFrag { ushort8 s; bf16x8 b; };

__device__ __forceinline__ unsigned short f2bf(float f) {
    unsigned int u = __float_as_uint(f);
    u = (u + 0x7FFFu + ((u >> 16) & 1u)) >> 16;   // RNE
    return (unsigned short)u;
}

// decode 2x(2 bf16) -> float4
__device__ __forceinline__ float4 bf4(unsigned int lo, unsigned int hi) {
    float4 v;
    v.x = __uint_as_float(lo << 16);
    v.y = __uint_as_float(lo & 0xFFFF0000u);
    v.z = __uint_as_float(hi << 16);
    v.w = __uint_as_float(hi & 0xFFFF0000u);
    return v;
}

// ---------------------------------------------------------------------------
// K0: setup — Wt[h][k] = bf16(W[k][h]) only.
// ---------------------------------------------------------------------------
__global__ __launch_bounds__(256) void setup_wt(const float* __restrict__ W,
                                                unsigned short* __restrict__ Wt) {
    const int i = blockIdx.x * 256 + threadIdx.x;
    const int h = i >> 8;
    const int k = i & 255;
    Wt[i] = f2bf(W[k * NHID + h]);
}

// ---------------------------------------------------------------------------
// K1: GEMM (blocks [0,625)) || fill (blocks [625,875)).
// R16: GEMM path x-loads were per-lane row gathers (16 lanes x 16 different
// 1KB-strided rows -> one transaction per 16B; K1 stuck at 41-43us across
// four fill redesigns). Now: coalesced float4 staging of the 64x256 tile
// -> bf16 -> LDS [64][264] (pad -> 2 lanes/bank on ds_read_b128 = free),
// fragments from LDS. Fill path unchanged (proven R13-R15).
// ---------------------------------------------------------------------------
__global__ __launch_bounds__(256) void gemm_fill(const float* __restrict__ x,
                                                 const unsigned short* __restrict__ Wt,
                                                 unsigned short* __restrict__ support,
                                                 const int* __restrict__ ei,
                                                 const float* __restrict__ ew,
                                                 unsigned long long* __restrict__ ebin) {
    const int tid = threadIdx.x;

    if (blockIdx.x >= GEMM_BLOCKS) {
        // ---- fill path ----
        __shared__ unsigned int ldscur[NW];          // 5000 B
        const int pb   = blockIdx.x - GEMM_BLOCKS;
        const int base = pb * EPB + tid;

        for (int i = tid; i < NW; i += 256) ldscur[i] = 0u;
        __syncthreads();

        int src[EPT], dst[EPT];
        float w[EPT];
        #pragma unroll
        for (int j = 0; j < EPT; j++) {
            const int e = base + j * 256;
            src[j] = ei[e];
            dst[j] = ei[NEDGES + e];
            w[j]   = ew[e];
        }
        #pragma unroll
        for (int j = 0; j < EPT; j++) {
            const int rw = dst[j] >> WSH;
            const unsigned int idx = atomicAdd(&ldscur[rw], 1u);
            if (idx < CAPREC) {
                const unsigned long long rec =
                    ((unsigned long long)f2bf(w[j]) << 32)
                  | ((unsigned long long)(dst[j] & (WNODES - 1)) << 16)
                  | (unsigned long long)(unsigned int)src[j];
                ebin[((size_t)rw * PARTB + pb) * CSLOTS + 1 + idx] = rec;
            }
        }
        __syncthreads();

        for (int i = tid; i < NW; i += 256) {        // strided (R10 lesson)
            unsigned int c = ldscur[i];
            if (c > CAPREC) c = CAPREC;
            ebin[((size_t)i * PARTB + pb) * CSLOTS] = (unsigned long long)c;
        }
        return;
    }

    // ---- GEMM path: coalesced LDS staging (R16) ----
    __shared__ unsigned short xs[64 * XPAD];         // 33,792 B
    const int node0 = blockIdx.x * 64;
    {
        const float4* xg = (const float4*)(x + (size_t)node0 * NFEAT);
        for (int j = tid; j < 64 * 64; j += 256) {   // 4096 float4, coalesced
            const float4 f = xg[j];
            const int row = j >> 6;
            const int c4  = j & 63;
            unsigned short* p = xs + row * XPAD + c4 * 4;
            p[0] = f2bf(f.x); p[1] = f2bf(f.y);
            p[2] = f2bf(f.z); p[3] = f2bf(f.w);
        }
    }
    __syncthreads();

    const int lane = tid & 63;
    const int wv   = tid >> 6;
    const int m    = lane & 15;
    const int quad = lane >> 4;

    BfFrag afrag[8];
    const unsigned short* xrow = xs + (wv * 16 + m) * XPAD + quad * 8;
    #pragma unroll
    for (int ks = 0; ks < 8; ks++)
        afrag[ks].s = *(const ushort8*)(xrow + ks * 32);

    floatx4 acc[8];
    #pragma unroll
    for (int nt = 0; nt < 8; nt++) acc[nt] = (floatx4){0.f, 0.f, 0.f, 0.f};

    #pragma unroll
    for (int nt = 0; nt < 8; nt++) {
        const unsigned short* wrow = Wt + (size_t)(nt * 16 + m) * NFEAT + quad * 8;
        #pragma unroll
        for (int ks = 0; ks < 8; ks++) {
            BfFrag bfrag;
            bfrag.s = *(const ushort8*)(wrow + ks * 32);
            acc[nt] = __builtin_amdgcn_mfma_f32_16x16x32_bf16(afrag[ks].b, bfrag.b,
                                                              acc[nt], 0, 0, 0);
        }
    }

    const int row0 = node0 + wv * 16 + quad * 4;
    #pragma unroll
    for (int nt = 0; nt < 8; nt++) {
        #pragma unroll
        for (int r = 0; r < 4; r++) {
            support[(size_t)(row0 + r) * NHID + nt * 16 + m] = f2bf(acc[nt][r]);
        }
    }
}

// ---------------------------------------------------------------------------
// K2: gather — one block (512 thr) per 32-node window, 1250 blocks.
// R15-proven (151.8us wall): phase A stages each cell's first line (header
// + 7 records, P~99.9% coverage) into LDS with coalesced uint4 loads by all
// 512 threads; histogram + scatter slot-parallel over LDS; rare >7-record
// cells take a global overflow path. Walk: 16 lanes/node, 8 hids/lane.
// Zero fp atomics.
// ---------------------------------------------------------------------------
__global__ __launch_bounds__(512) void gather_range(
        const unsigned long long* __restrict__ ebin,
        const unsigned short* __restrict__ support,
        const float* __restrict__ b,
        float* __restrict__ out) {
    __shared__ unsigned long long cells[PARTB * 8];  // 16000 B: line0 of each cell
    __shared__ unsigned long long srec[CAPW];        // 8192 B
    __shared__ unsigned int hcnt[WNODES];
    __shared__ unsigned int hstart[WNODES + 1];
    __shared__ unsigned int sA[WNODES], sB[WNODES];

    const int rw  = blockIdx.x;                      // window: nodes [rw*32, rw*32+32)
    const int tid = threadIdx.x;
    const unsigned long long* gbase = ebin + (size_t)rw * PARTB * CSLOTS;

    // phase A: coalesced stage of cell first-lines (header + records 0..6)
    {
        const uint4* g4 = (const uint4*)gbase;       // cell c line0 = g4[c*8 + 0..3]
        uint4*       l4 = (uint4*)cells;             // LDS [c*4 + 0..3]
        for (int i = tid; i < PARTB * 4; i += 512) {
            const int c = i >> 2, p = i & 3;
            l4[i] = g4[c * 8 + p];
        }
    }
    if (tid < WNODES) hcnt[tid] = 0u;
    __syncthreads();

    // phase B: histogram dl — slot-parallel over LDS (all threads)
    for (int i = tid; i < PARTB * 7; i += 512) {
        const int c = i / 7, s = i - c * 7;
        unsigned int ct = (unsigned int)cells[c * 8];
        if (ct > CAPREC) ct = CAPREC;
        const unsigned int c7 = ct < 7u ? ct : 7u;
        if ((unsigned int)s < c7)
            atomicAdd(&hcnt[(unsigned int)(cells[c * 8 + 1 + s] >> 16) & (WNODES - 1)], 1u);
    }
    for (int c = tid; c < PARTB; c += 512) {         // overflow: records 7..ct-1
        unsigned int ct = (unsigned int)cells[c * 8];
        if (ct > CAPREC) ct = CAPREC;
        for (unsigned int k = 7; k < ct; ++k)
            atomicAdd(&hcnt[(unsigned int)(gbase[(size_t)c * CSLOTS + 1 + k] >> 16) & (WNODES - 1)], 1u);
    }
    __syncthreads();

    // exclusive scan over 32 (Hillis-Steele, 5 passes)
    if (tid < WNODES) sA[tid] = (tid > 0) ? hcnt[tid - 1] : 0u;
    __syncthreads();
    unsigned int* cur = sA;
    unsigned int* nxt = sB;
    for (int off = 1; off < WNODES; off <<= 1) {
        if (tid < WNODES) nxt[tid] = cur[tid] + ((tid >= off) ? cur[tid - off] : 0u);
        __syncthreads();
        unsigned int* t = cur; cur = nxt; nxt = t;
    }
    if (tid < WNODES) hstart[tid] = cur[tid];
    if (tid == WNODES - 1) hstart[WNODES] = cur[WNODES - 1] + hcnt[WNODES - 1];
    __syncthreads();
    if (tid < WNODES) hcnt[tid] = hstart[tid];       // becomes scatter cursor
    __syncthreads();

    // phase C: scatter into dl-sorted srec — slot-parallel over LDS
    for (int i = tid; i < PARTB * 7; i += 512) {
        const int c = i / 7, s = i - c * 7;
        unsigned int ct = (unsigned int)cells[c * 8];
        if (ct > CAPREC) ct = CAPREC;
        const unsigned int c7 = ct < 7u ? ct : 7u;
        if ((unsigned int)s < c7) {
            const unsigned long long rec = cells[c * 8 + 1 + s];
            const unsigned int dl = (unsigned int)(rec >> 16) & (WNODES - 1);
            const unsigned int p  = atomicAdd(&hcnt[dl], 1u);
            if (p < CAPW) srec[p] = rec;
        }
    }
    for (int c = tid; c < PARTB; c += 512) {         // overflow: records 7..ct-1
        unsigned int ct = (unsigned int)cells[c * 8];
        if (ct > CAPREC) ct = CAPREC;
        for (unsigned int k = 7; k < ct; ++k) {
            const unsigned long long rec = gbase[(size_t)c * CSLOTS + 1 + k];
            const unsigned int dl = (unsigned int)(rec >> 16) & (WNODES - 1);
            const unsigned int p  = atomicAdd(&hcnt[dl], 1u);
            if (p < CAPW) srec[p] = rec;
        }
    }
    __syncthreads();

    // walk: 16 lanes per node, 8 hids per lane, 1 uint4 per record
    const int nl = tid >> 4;            // 0..31
    const int ql = tid & 15;            // hids [8*ql, 8*ql+8)
    unsigned int kb = hstart[nl];
    unsigned int ke = hstart[nl + 1];
    if (kb > CAPW) kb = CAPW;
    if (ke > CAPW) ke = CAPW;

    float4 lo = make_float4(0.f, 0.f, 0.f, 0.f);
    float4 hi = lo;
    const uint4* sup4 = (const uint4*)support;       // 16 uint4 per row

    #pragma unroll 2
    for (unsigned int k = kb; k < ke; ++k) {
        const unsigned long long rec = srec[k];      // broadcast in 16-lane group
        const float w  = __uint_as_float(((unsigned int)(rec >> 32)) << 16);
        const int   sc = (int)(rec & 0xFFFFu);
        const uint4 u  = sup4[(size_t)sc * 16 + ql];
        const float4 vl = bf4(u.x, u.y), vh = bf4(u.z, u.w);
        lo.x = fmaf(w, vl.x, lo.x); lo.y = fmaf(w, vl.y, lo.y);
        lo.z = fmaf(w, vl.z, lo.z); lo.w = fmaf(w, vl.w, lo.w);
        hi.x = fmaf(w, vh.x, hi.x); hi.y = fmaf(w, vh.y, hi.y);
        hi.z = fmaf(w, vh.z, hi.z); hi.w = fmaf(w, vh.w, hi.w);
    }

    // epilogue: bias + relu + direct store (lane owns hids exclusively)
    const int node = rw * WNODES + nl;               // < 40000 by construction
    {
        const float4* b4p = (const float4*)b;
        float4 bl = b4p[ql * 2], bh = b4p[ql * 2 + 1];
        lo.x = fmaxf(lo.x + bl.x, 0.f); lo.y = fmaxf(lo.y + bl.y, 0.f);
        lo.z = fmaxf(lo.z + bl.z, 0.f); lo.w = fmaxf(lo.w + bl.w, 0.f);
        hi.x = fmaxf(hi.x + bh.x, 0.f); hi.y = fmaxf(hi.y + bh.y, 0.f);
        hi.z = fmaxf(hi.z + bh.z, 0.f); hi.w = fmaxf(hi.w + bh.w, 0.f);
        float4* o4 = (float4*)out + (size_t)node * (NHID / 4);
        o4[ql * 2]     = lo;
        o4[ql * 2 + 1] = hi;
    }
}

// ---------------------------------------------------------------------------
// Fallback path (ws too small): fp32 GEMM + atomic scatter
// ---------------------------------------------------------------------------
__global__ __launch_bounds__(256) void gemm_xw(const float* __restrict__ x,
                                               const float* __restrict__ W,
                                               float* __restrict__ support) {
    __shared__ float xsf[64 * NFEAT];
    const int tid   = threadIdx.x;
    const int node0 = blockIdx.x * 64;

    const float4* xg  = (const float4*)(x + (size_t)node0 * NFEAT);
    float4*       xs4 = (float4*)xsf;
    #pragma unroll
    for (int i = tid; i < 64 * (NFEAT / 4); i += 256) xs4[i] = xg[i];
    __syncthreads();

    const int hg = tid & 31;
    const int ng = tid >> 5;
    const float4* W4 = (const float4*)W;

    float4 acc[8];
    #pragma unroll
    for (int n = 0; n < 8; n++) acc[n] = make_float4(0.f, 0.f, 0.f, 0.f);

    #pragma unroll 4
    for (int k = 0; k < NFEAT; k++) {
        float4 w = W4[k * (NHID / 4) + hg];
        #pragma unroll
        for (int n = 0; n < 8; n++) {
            float xv = xsf[(ng * 8 + n) * NFEAT + k];
            acc[n].x = fmaf(xv, w.x, acc[n].x);
            acc[n].y = fmaf(xv, w.y, acc[n].y);
            acc[n].z = fmaf(xv, w.z, acc[n].z);
            acc[n].w = fmaf(xv, w.w, acc[n].w);
        }
    }

    float4* out4 = (float4*)support;
    #pragma unroll
    for (int n = 0; n < 8; n++)
        out4[(size_t)(node0 + ng * 8 + n) * (NHID / 4) + hg] = acc[n];
}

__global__ __launch_bounds__(256) void scatter_edges(const int* __restrict__ ei,
                                                     const float* __restrict__ ew,
                                                     const float* __restrict__ support,
                                                     float* __restrict__ out) {
    const int tid  = threadIdx.x;
    const int lane = tid & 31;
    const int e    = blockIdx.x * 8 + (tid >> 5);
    const int   src = ei[e];
    const int   dst = ei[NEDGES + e];
    const float w   = ew[e];
    const float4* s4 = (const float4*)support;
    float4 v = s4[(size_t)src * (NHID / 4) + lane];
    float* o = out + (size_t)dst * NHID + lane * 4;
    atomicAdd(o + 0, v.x * w);
    atomicAdd(o + 1, v.y * w);
    atomicAdd(o + 2, v.z * w);
    atomicAdd(o + 3, v.w * w);
}

__global__ __launch_bounds__(256) void finalize(float* __restrict__ out,
                                                const float* __restrict__ b) {
    const int i = blockIdx.x * 256 + threadIdx.x;
    float4*       o4 = (float4*)out;
    const float4* b4 = (const float4*)b;
    float4 v  = o4[i];
    float4 bb = b4[i & 31];
    v.x = fmaxf(v.x + bb.x, 0.f);
    v.y = fmaxf(v.y + bb.y, 0.f);
    v.z = fmaxf(v.z + bb.z, 0.f);
    v.w = fmaxf(v.w + bb.w, 0.f);
    o4[i] = v;
}

extern "C" void kernel_launch(void* const* d_in, const int* in_sizes, int n_in,
                              void* d_out, int out_size, void* d_ws, size_t ws_size,
                              hipStream_t stream) {
    const float* x  = (const float*)d_in[0];
    const int*   ei = (const int*)d_in[1];
    const float* ew = (const float*)d_in[2];
    const float* W  = (const float*)d_in[3];
    const float* b  = (const float*)d_in[4];
    float*       out = (float*)d_out;

    char* ws = (char*)d_ws;

    if (ws_size >= WS_NEEDED) {
        unsigned short*     support = (unsigned short*)(ws + SUP_OFF);
        unsigned short*     Wt      = (unsigned short*)(ws + WT_OFF);
        unsigned long long* ebin    = (unsigned long long*)(ws + EBIN_OFF);

        setup_wt<<<128, 256, 0, stream>>>(W, Wt);
        gemm_fill<<<GEMM_BLOCKS + PARTB, 256, 0, stream>>>(
            x, Wt, support, ei, ew, ebin);
        gather_range<<<NW, 512, 0, stream>>>(ebin, support, b, out);
    } else {
        float* support = (float*)(ws + SUP_OFF);
        gemm_xw<<<NNODES / 64, 256, 0, stream>>>(x, W, support);
        hipMemsetAsync(d_out, 0, (size_t)out_size * sizeof(float), stream);
        scatter_edges<<<NEDGES / 8, 256, 0, stream>>>(ei, ew, support, out);
        finalize<<<out_size / 4 / 256, 256, 0, stream>>>(out, b);
    }
}

// Round 18
// 148.771 us; speedup vs baseline: 1.1018x; 1.1018x over previous
//
#include <hip/hip_runtime.h>

#define NNODES 40000
#define NEDGES 640000
#define NFEAT  256
#define NHID   128

// ---- window partition geometry ----
#define WSH    5                        // 32 nodes per window
#define WNODES 32
#define NW     1250                     // 40000/32 exactly
#define PARTB  250                      // fill blocks
#define EPT    10
#define EPB    2560                     // edges per fill block
#define CSLOTS 16                       // cell = 1 header u64 + 15 record slots
#define CAPREC 15                       // records per cell; lambda=2.05, P(>15)~6e-10
#define CAPW   1024                     // gather srec cap; E[cnt]=512
#define GEMM_BLOCKS (NNODES / 64)       // 625

// ---- workspace layout (bytes; ws_size = 256 MiB per R9 poison evidence) ----
#define SUP_OFF  0u                     // support bf16: 10,240,000
#define WT_OFF   10240000u              // Wt bf16: 65,536
#define EBIN_OFF 10305536u              // ebin u64 [NW][PARTB][CSLOTS]: 40,000,000
#define WS_NEEDED (EBIN_OFF + (size_t)NW * PARTB * CSLOTS * 8)   // 50,305,536

typedef float floatx4 __attribute__((ext_vector_type(4)));
typedef __bf16 bf16x8 __attribute__((ext_vector_type(8)));
typedef unsigned short ushort8 __attribute__((ext_vector_type(8)));
union BfFrag { ushort8 s; bf16x8 b; };

__device__ __forceinline__ unsigned short f2bf(float f) {
    unsigned int u = __float_as_uint(f);
    u = (u + 0x7FFFu + ((u >> 16) & 1u)) >> 16;   // RNE
    return (unsigned short)u;
}

// decode 2x(2 bf16) -> float4
__device__ __forceinline__ float4 bf4(unsigned int lo, unsigned int hi) {
    float4 v;
    v.x = __uint_as_float(lo << 16);
    v.y = __uint_as_float(lo & 0xFFFF0000u);
    v.z = __uint_as_float(hi << 16);
    v.w = __uint_as_float(hi & 0xFFFF0000u);
    return v;
}

// ---------------------------------------------------------------------------
// K0: setup — Wt[h][k] = bf16(W[k][h]) only.
// ---------------------------------------------------------------------------
__global__ __launch_bounds__(256) void setup_wt(const float* __restrict__ W,
                                                unsigned short* __restrict__ Wt) {
    const int i = blockIdx.x * 256 + threadIdx.x;
    const int h = i >> 8;
    const int k = i & 255;
    Wt[i] = f2bf(W[k * NHID + h]);
}

// ---------------------------------------------------------------------------
// K1: GEMM (blocks [0,625)) || fill (blocks [625,875)).
// R17 lesson: LDS-staging the x-tile REGRESSED (41->53us; 450K bank
// conflicts on staging writes + serialized read phase). Direct per-lane
// global x-loads (R15 form) are the proven floor — latency hidden by
// ~5 resident blocks/CU. Fill path proven R13-R15: block pb owns cell
// [rw][pb] (header u64 + 15 slots); LDS u32 counter gives slot; header
// written into the block's own private line.
// ---------------------------------------------------------------------------
__global__ __launch_bounds__(256) void gemm_fill(const float* __restrict__ x,
                                                 const unsigned short* __restrict__ Wt,
                                                 unsigned short* __restrict__ support,
                                                 const int* __restrict__ ei,
                                                 const float* __restrict__ ew,
                                                 unsigned long long* __restrict__ ebin) {
    const int tid = threadIdx.x;

    if (blockIdx.x >= GEMM_BLOCKS) {
        // ---- fill path ----
        __shared__ unsigned int ldscur[NW];          // 5000 B
        const int pb   = blockIdx.x - GEMM_BLOCKS;
        const int base = pb * EPB + tid;

        for (int i = tid; i < NW; i += 256) ldscur[i] = 0u;
        __syncthreads();

        int src[EPT], dst[EPT];
        float w[EPT];
        #pragma unroll
        for (int j = 0; j < EPT; j++) {
            const int e = base + j * 256;
            src[j] = ei[e];
            dst[j] = ei[NEDGES + e];
            w[j]   = ew[e];
        }
        #pragma unroll
        for (int j = 0; j < EPT; j++) {
            const int rw = dst[j] >> WSH;
            const unsigned int idx = atomicAdd(&ldscur[rw], 1u);
            if (idx < CAPREC) {
                const unsigned long long rec =
                    ((unsigned long long)f2bf(w[j]) << 32)
                  | ((unsigned long long)(dst[j] & (WNODES - 1)) << 16)
                  | (unsigned long long)(unsigned int)src[j];
                ebin[((size_t)rw * PARTB + pb) * CSLOTS + 1 + idx] = rec;
            }
        }
        __syncthreads();

        for (int i = tid; i < NW; i += 256) {        // strided (R10 lesson)
            unsigned int c = ldscur[i];
            if (c > CAPREC) c = CAPREC;
            ebin[((size_t)i * PARTB + pb) * CSLOTS] = (unsigned long long)c;
        }
        return;
    }

    // ---- GEMM path (R15-proven: direct global x-loads) ----
    const int lane = tid & 63;
    const int wv   = tid >> 6;
    const int m    = lane & 15;
    const int quad = lane >> 4;
    const int node = blockIdx.x * 64 + wv * 16 + m;

    BfFrag afrag[8];
    const float* xrow = x + (size_t)node * NFEAT + quad * 8;
    #pragma unroll
    for (int ks = 0; ks < 8; ks++) {
        float4 f0 = *(const float4*)(xrow + ks * 32);
        float4 f1 = *(const float4*)(xrow + ks * 32 + 4);
        afrag[ks].s[0] = f2bf(f0.x); afrag[ks].s[1] = f2bf(f0.y);
        afrag[ks].s[2] = f2bf(f0.z); afrag[ks].s[3] = f2bf(f0.w);
        afrag[ks].s[4] = f2bf(f1.x); afrag[ks].s[5] = f2bf(f1.y);
        afrag[ks].s[6] = f2bf(f1.z); afrag[ks].s[7] = f2bf(f1.w);
    }

    floatx4 acc[8];
    #pragma unroll
    for (int nt = 0; nt < 8; nt++) acc[nt] = (floatx4){0.f, 0.f, 0.f, 0.f};

    #pragma unroll
    for (int nt = 0; nt < 8; nt++) {
        const unsigned short* wrow = Wt + (size_t)(nt * 16 + m) * NFEAT + quad * 8;
        #pragma unroll
        for (int ks = 0; ks < 8; ks++) {
            BfFrag bfrag;
            bfrag.s = *(const ushort8*)(wrow + ks * 32);
            acc[nt] = __builtin_amdgcn_mfma_f32_16x16x32_bf16(afrag[ks].b, bfrag.b,
                                                              acc[nt], 0, 0, 0);
        }
    }

    const int row0 = blockIdx.x * 64 + wv * 16 + quad * 4;
    #pragma unroll
    for (int nt = 0; nt < 8; nt++) {
        #pragma unroll
        for (int r = 0; r < 4; r++) {
            support[(size_t)(row0 + r) * NHID + nt * 16 + m] = f2bf(acc[nt][r]);
        }
    }
}

// ---------------------------------------------------------------------------
// K2: gather — one block (512 thr) per 32-node window, 1250 blocks.
// R15-proven (151.8us wall): phase A stages each cell's first line (header
// + 7 records, P~99.9% coverage) into LDS with coalesced uint4 loads by all
// 512 threads; histogram + scatter slot-parallel over LDS; rare >7-record
// cells take a global overflow path. Walk: 16 lanes/node, 8 hids/lane.
// Zero fp atomics.
// ---------------------------------------------------------------------------
__global__ __launch_bounds__(512) void gather_range(
        const unsigned long long* __restrict__ ebin,
        const unsigned short* __restrict__ support,
        const float* __restrict__ b,
        float* __restrict__ out) {
    __shared__ unsigned long long cells[PARTB * 8];  // 16000 B: line0 of each cell
    __shared__ unsigned long long srec[CAPW];        // 8192 B
    __shared__ unsigned int hcnt[WNODES];
    __shared__ unsigned int hstart[WNODES + 1];
    __shared__ unsigned int sA[WNODES], sB[WNODES];

    const int rw  = blockIdx.x;                      // window: nodes [rw*32, rw*32+32)
    const int tid = threadIdx.x;
    const unsigned long long* gbase = ebin + (size_t)rw * PARTB * CSLOTS;

    // phase A: coalesced stage of cell first-lines (header + records 0..6)
    {
        const uint4* g4 = (const uint4*)gbase;       // cell c line0 = g4[c*8 + 0..3]
        uint4*       l4 = (uint4*)cells;             // LDS [c*4 + 0..3]
        for (int i = tid; i < PARTB * 4; i += 512) {
            const int c = i >> 2, p = i & 3;
            l4[i] = g4[c * 8 + p];
        }
    }
    if (tid < WNODES) hcnt[tid] = 0u;
    __syncthreads();

    // phase B: histogram dl — slot-parallel over LDS (all threads)
    for (int i = tid; i < PARTB * 7; i += 512) {
        const int c = i / 7, s = i - c * 7;
        unsigned int ct = (unsigned int)cells[c * 8];
        if (ct > CAPREC) ct = CAPREC;
        const unsigned int c7 = ct < 7u ? ct : 7u;
        if ((unsigned int)s < c7)
            atomicAdd(&hcnt[(unsigned int)(cells[c * 8 + 1 + s] >> 16) & (WNODES - 1)], 1u);
    }
    for (int c = tid; c < PARTB; c += 512) {         // overflow: records 7..ct-1
        unsigned int ct = (unsigned int)cells[c * 8];
        if (ct > CAPREC) ct = CAPREC;
        for (unsigned int k = 7; k < ct; ++k)
            atomicAdd(&hcnt[(unsigned int)(gbase[(size_t)c * CSLOTS + 1 + k] >> 16) & (WNODES - 1)], 1u);
    }
    __syncthreads();

    // exclusive scan over 32 (Hillis-Steele, 5 passes)
    if (tid < WNODES) sA[tid] = (tid > 0) ? hcnt[tid - 1] : 0u;
    __syncthreads();
    unsigned int* cur = sA;
    unsigned int* nxt = sB;
    for (int off = 1; off < WNODES; off <<= 1) {
        if (tid < WNODES) nxt[tid] = cur[tid] + ((tid >= off) ? cur[tid - off] : 0u);
        __syncthreads();
        unsigned int* t = cur; cur = nxt; nxt = t;
    }
    if (tid < WNODES) hstart[tid] = cur[tid];
    if (tid == WNODES - 1) hstart[WNODES] = cur[WNODES - 1] + hcnt[WNODES - 1];
    __syncthreads();
    if (tid < WNODES) hcnt[tid] = hstart[tid];       // becomes scatter cursor
    __syncthreads();

    // phase C: scatter into dl-sorted srec — slot-parallel over LDS
    for (int i = tid; i < PARTB * 7; i += 512) {
        const int c = i / 7, s = i - c * 7;
        unsigned int ct = (unsigned int)cells[c * 8];
        if (ct > CAPREC) ct = CAPREC;
        const unsigned int c7 = ct < 7u ? ct : 7u;
        if ((unsigned int)s < c7) {
            const unsigned long long rec = cells[c * 8 + 1 + s];
            const unsigned int dl = (unsigned int)(rec >> 16) & (WNODES - 1);
            const unsigned int p  = atomicAdd(&hcnt[dl], 1u);
            if (p < CAPW) srec[p] = rec;
        }
    }
    for (int c = tid; c < PARTB; c += 512) {         // overflow: records 7..ct-1
        unsigned int ct = (unsigned int)cells[c * 8];
        if (ct > CAPREC) ct = CAPREC;
        for (unsigned int k = 7; k < ct; ++k) {
            const unsigned long long rec = gbase[(size_t)c * CSLOTS + 1 + k];
            const unsigned int dl = (unsigned int)(rec >> 16) & (WNODES - 1);
            const unsigned int p  = atomicAdd(&hcnt[dl], 1u);
            if (p < CAPW) srec[p] = rec;
        }
    }
    __syncthreads();

    // walk: 16 lanes per node, 8 hids per lane, 1 uint4 per record
    const int nl = tid >> 4;            // 0..31
    const int ql = tid & 15;            // hids [8*ql, 8*ql+8)
    unsigned int kb = hstart[nl];
    unsigned int ke = hstart[nl + 1];
    if (kb > CAPW) kb = CAPW;
    if (ke > CAPW) ke = CAPW;

    float4 lo = make_float4(0.f, 0.f, 0.f, 0.f);
    float4 hi = lo;
    const uint4* sup4 = (const uint4*)support;       // 16 uint4 per row

    #pragma unroll 2
    for (unsigned int k = kb; k < ke; ++k) {
        const unsigned long long rec = srec[k];      // broadcast in 16-lane group
        const float w  = __uint_as_float(((unsigned int)(rec >> 32)) << 16);
        const int   sc = (int)(rec & 0xFFFFu);
        const uint4 u  = sup4[(size_t)sc * 16 + ql];
        const float4 vl = bf4(u.x, u.y), vh = bf4(u.z, u.w);
        lo.x = fmaf(w, vl.x, lo.x); lo.y = fmaf(w, vl.y, lo.y);
        lo.z = fmaf(w, vl.z, lo.z); lo.w = fmaf(w, vl.w, lo.w);
        hi.x = fmaf(w, vh.x, hi.x); hi.y = fmaf(w, vh.y, hi.y);
        hi.z = fmaf(w, vh.z, hi.z); hi.w = fmaf(w, vh.w, hi.w);
    }

    // epilogue: bias + relu + direct store (lane owns hids exclusively)
    const int node = rw * WNODES + nl;               // < 40000 by construction
    {
        const float4* b4p = (const float4*)b;
        float4 bl = b4p[ql * 2], bh = b4p[ql * 2 + 1];
        lo.x = fmaxf(lo.x + bl.x, 0.f); lo.y = fmaxf(lo.y + bl.y, 0.f);
        lo.z = fmaxf(lo.z + bl.z, 0.f); lo.w = fmaxf(lo.w + bl.w, 0.f);
        hi.x = fmaxf(hi.x + bh.x, 0.f); hi.y = fmaxf(hi.y + bh.y, 0.f);
        hi.z = fmaxf(hi.z + bh.z, 0.f); hi.w = fmaxf(hi.w + bh.w, 0.f);
        float4* o4 = (float4*)out + (size_t)node * (NHID / 4);
        o4[ql * 2]     = lo;
        o4[ql * 2 + 1] = hi;
    }
}

// ---------------------------------------------------------------------------
// Fallback path (ws too small): fp32 GEMM + atomic scatter
// ---------------------------------------------------------------------------
__global__ __launch_bounds__(256) void gemm_xw(const float* __restrict__ x,
                                               const float* __restrict__ W,
                                               float* __restrict__ support) {
    __shared__ float xsf[64 * NFEAT];
    const int tid   = threadIdx.x;
    const int node0 = blockIdx.x * 64;

    const float4* xg  = (const float4*)(x + (size_t)node0 * NFEAT);
    float4*       xs4 = (float4*)xsf;
    #pragma unroll
    for (int i = tid; i < 64 * (NFEAT / 4); i += 256) xs4[i] = xg[i];
    __syncthreads();

    const int hg = tid & 31;
    const int ng = tid >> 5;
    const float4* W4 = (const float4*)W;

    float4 acc[8];
    #pragma unroll
    for (int n = 0; n < 8; n++) acc[n] = make_float4(0.f, 0.f, 0.f, 0.f);

    #pragma unroll 4
    for (int k = 0; k < NFEAT; k++) {
        float4 w = W4[k * (NHID / 4) + hg];
        #pragma unroll
        for (int n = 0; n < 8; n++) {
            float xv = xsf[(ng * 8 + n) * NFEAT + k];
            acc[n].x = fmaf(xv, w.x, acc[n].x);
            acc[n].y = fmaf(xv, w.y, acc[n].y);
            acc[n].z = fmaf(xv, w.z, acc[n].z);
            acc[n].w = fmaf(xv, w.w, acc[n].w);
        }
    }

    float4* out4 = (float4*)support;
    #pragma unroll
    for (int n = 0; n < 8; n++)
        out4[(size_t)(node0 + ng * 8 + n) * (NHID / 4) + hg] = acc[n];
}

__global__ __launch_bounds__(256) void scatter_edges(const int* __restrict__ ei,
                                                     const float* __restrict__ ew,
                                                     const float* __restrict__ support,
                                                     float* __restrict__ out) {
    const int tid  = threadIdx.x;
    const int lane = tid & 31;
    const int e    = blockIdx.x * 8 + (tid >> 5);
    const int   src = ei[e];
    const int   dst = ei[NEDGES + e];
    const float w   = ew[e];
    const float4* s4 = (const float4*)support;
    float4 v = s4[(size_t)src * (NHID / 4) + lane];
    float* o = out + (size_t)dst * NHID + lane * 4;
    atomicAdd(o + 0, v.x * w);
    atomicAdd(o + 1, v.y * w);
    atomicAdd(o + 2, v.z * w);
    atomicAdd(o + 3, v.w * w);
}

__global__ __launch_bounds__(256) void finalize(float* __restrict__ out,
                                                const float* __restrict__ b) {
    const int i = blockIdx.x * 256 + threadIdx.x;
    float4*       o4 = (float4*)out;
    const float4* b4 = (const float4*)b;
    float4 v  = o4[i];
    float4 bb = b4[i & 31];
    v.x = fmaxf(v.x + bb.x, 0.f);
    v.y = fmaxf(v.y + bb.y, 0.f);
    v.z = fmaxf(v.z + bb.z, 0.f);
    v.w = fmaxf(v.w + bb.w, 0.f);
    o4[i] = v;
}

extern "C" void kernel_launch(void* const* d_in, const int* in_sizes, int n_in,
                              void* d_out, int out_size, void* d_ws, size_t ws_size,
                              hipStream_t stream) {
    const float* x  = (const float*)d_in[0];
    const int*   ei = (const int*)d_in[1];
    const float* ew = (const float*)d_in[2];
    const float* W  = (const float*)d_in[3];
    const float* b  = (const float*)d_in[4];
    float*       out = (float*)d_out;

    char* ws = (char*)d_ws;

    if (ws_size >= WS_NEEDED) {
        unsigned short*     support = (unsigned short*)(ws + SUP_OFF);
        unsigned short*     Wt      = (unsigned short*)(ws + WT_OFF);
        unsigned long long* ebin    = (unsigned long long*)(ws + EBIN_OFF);

        setup_wt<<<128, 256, 0, stream>>>(W, Wt);
        gemm_fill<<<GEMM_BLOCKS + PARTB, 256, 0, stream>>>(
            x, Wt, support, ei, ew, ebin);
        gather_range<<<NW, 512, 0, stream>>>(ebin, support, b, out);
    } else {
        float* support = (float*)(ws + SUP_OFF);
        gemm_xw<<<NNODES / 64, 256, 0, stream>>>(x, W, support);
        hipMemsetAsync(d_out, 0, (size_t)out_size * sizeof(float), stream);
        scatter_edges<<<NEDGES / 8, 256, 0, stream>>>(ei, ew, support, out);
        finalize<<<out_size / 4 / 256, 256, 0, stream>>>(out, b);
    }
}